// Round 6
// baseline (417.322 us; speedup 1.0000x reference)
//
#include <hip/hip_runtime.h>

// NeighborList: N=4096, cutoff 5.0, all pairs i<j (P = N(N-1)/2 = 8,386,560).
// Output (floats): [0,P) pair_i | [P,2P) pair_j | [2P,5P) diff[P,3] | [5P,6P) dist | [6P] n_pairs
//
// R5: linear-p, 8 pairs/thread (P = 2048*4095 exactly -> nb=4095, no tail),
// two 4-pair aligned float4 store groups. Plain stores (R3 lesson: nontemporal
// stores cost 3x write BW on gfx950). Count fused: memset ticket to 0 each
// call (graph-legal), per-block release-store + ACQ_REL ticket; the true last
// block (old == nb-1, exact now that start is 0) sums and writes n_pairs.

typedef float f4 __attribute__((ext_vector_type(4)));

__global__ void zero_ws(int* __restrict__ ws, int n) {
    int t = blockIdx.x * blockDim.x + threadIdx.x;
    if (t < n) ws[t] = 0;
}

__global__ __launch_bounds__(256) void nl_kernel(const float* __restrict__ xyz,
                                                 float* __restrict__ out,
                                                 int* __restrict__ ws,
                                                 int N, int P, int slots, int fused) {
    const int base = (blockIdx.x * 256 + threadIdx.x) * 8;
    int cnt = 0;
    if (base < P) {
        // invert p -> row i (rowstart(i) = i*(2N-1-i)/2 <= base); sqrtf of an
        // exactly-representable radicand gives i within +-2, int fixup exacts.
        const int twoNm1 = 2 * N - 1;
        const long long rad = (long long)twoNm1 * twoNm1 - 8LL * (long long)base;
        const float s = sqrtf((float)rad);
        int i = (int)(((float)twoNm1 - s) * 0.5f);
        if (i > N - 2) i = N - 2;
        if (i < 0) i = 0;
        int rs = i * (2 * N - 1 - i) / 2;
        while (base < rs) { --i; rs -= (N - 1 - i); }
        int next = rs + (N - 1 - i);
        while (base >= next && i < N - 2) { ++i; rs = next; next += (N - 1 - i); }

        #pragma unroll
        for (int g = 0; g < 2; ++g) {
            const int p0 = base + g * 4;
            float iv[4], jv[4], dxs[4], dys[4], dzs[4], dv[4];
            #pragma unroll
            for (int e = 0; e < 4; ++e) {
                const int p = p0 + e;
                while (p >= next && i < N - 2) { ++i; rs = next; next += (N - 1 - i); }
                const int j = i + 1 + (p - rs);
                float dx = 0.f, dy = 0.f, dz = 0.f, dist = 0.f, fi = -1.f, fj = -1.f;
                if (p < P) {
                    const float ax = xyz[3 * i], ay = xyz[3 * i + 1], az = xyz[3 * i + 2];
                    const float bx = xyz[3 * j], by = xyz[3 * j + 1], bz = xyz[3 * j + 2];
                    const float tx = ax - bx, ty = ay - by, tz = az - bz;
                    const float d = sqrtf(tx * tx + ty * ty + tz * tz);
                    if (d < 5.0f) {               // mirror reference: sqrt then compare
                        fi = (float)i; fj = (float)j;
                        dx = tx; dy = ty; dz = tz; dist = d;
                        ++cnt;
                    }
                }
                iv[e] = fi; jv[e] = fj; dxs[e] = dx; dys[e] = dy; dzs[e] = dz; dv[e] = dist;
            }

            if (p0 + 4 <= P) {   // p0 mult of 4 -> all 16B-aligned
                *(f4*)(out + p0)     = (f4){iv[0], iv[1], iv[2], iv[3]};
                *(f4*)(out + P + p0) = (f4){jv[0], jv[1], jv[2], jv[3]};
                f4* dp = (f4*)(out + 2 * P + 3 * p0);
                dp[0] = (f4){dxs[0], dys[0], dzs[0], dxs[1]};
                dp[1] = (f4){dys[1], dzs[1], dxs[2], dys[2]};
                dp[2] = (f4){dzs[2], dxs[3], dys[3], dzs[3]};
                *(f4*)(out + 5 * P + p0) = (f4){dv[0], dv[1], dv[2], dv[3]};
            } else {
                for (int e = 0; e < 4 && p0 + e < P; ++e) {
                    const int p = p0 + e;
                    out[p] = iv[e]; out[P + p] = jv[e];
                    out[2 * P + 3 * p]     = dxs[e];
                    out[2 * P + 3 * p + 1] = dys[e];
                    out[2 * P + 3 * p + 2] = dzs[e];
                    out[5 * P + p] = dv[e];
                }
            }
        }
    }

    // block-level count reduce
    for (int o = 32; o > 0; o >>= 1) cnt += __shfl_down(cnt, o, 64);
    __shared__ int sh[4];
    __shared__ int lastFlag;
    if ((threadIdx.x & 63) == 0) sh[threadIdx.x >> 6] = cnt;
    __syncthreads();
    const int nb = (int)gridDim.x;
    if (threadIdx.x == 0) {
        const int c = sh[0] + sh[1] + sh[2] + sh[3];
        if (fused) {
            // ticket ws[nb] was memset to 0 this call -> old == nb-1 is the
            // true last arrival; ACQ_REL RMW chain makes all prior release-
            // stores of counts visible to it (agent scope, cross-XCD).
            __hip_atomic_store(&ws[blockIdx.x], c, __ATOMIC_RELEASE, __HIP_MEMORY_SCOPE_AGENT);
            unsigned old = __hip_atomic_fetch_add((unsigned int*)&ws[nb], 1u,
                                                  __ATOMIC_ACQ_REL, __HIP_MEMORY_SCOPE_AGENT);
            lastFlag = (old == (unsigned)(nb - 1));
        } else {
            lastFlag = 0;
            if (nb <= slots) ws[blockIdx.x] = c;
            else if (c) atomicAdd(&ws[blockIdx.x % slots], c);
        }
    }
    __syncthreads();
    if (lastFlag) {  // block-uniform
        int s = 0;
        for (int k = threadIdx.x; k < nb; k += 256)
            s += __hip_atomic_load(&ws[k], __ATOMIC_RELAXED, __HIP_MEMORY_SCOPE_AGENT);
        for (int o = 32; o > 0; o >>= 1) s += __shfl_down(s, o, 64);
        if ((threadIdx.x & 63) == 0) sh[threadIdx.x >> 6] = s;
        __syncthreads();
        if (threadIdx.x == 0) out[6 * P] = (float)(sh[0] + sh[1] + sh[2] + sh[3]);
    }
}

__global__ void finalize_kernel(float* __restrict__ out, const int* __restrict__ ws,
                                int n, int pos) {
    const int t = threadIdx.x;  // 256
    int s = 0;
    for (int k = t; k < n; k += 256) s += ws[k];
    for (int o = 32; o > 0; o >>= 1) s += __shfl_down(s, o, 64);
    __shared__ int sh[4];
    if ((t & 63) == 0) sh[t >> 6] = s;
    __syncthreads();
    if (t == 0) out[pos] = (float)(sh[0] + sh[1] + sh[2] + sh[3]);
}

extern "C" void kernel_launch(void* const* d_in, const int* in_sizes, int n_in,
                              void* d_out, int out_size, void* d_ws, size_t ws_size,
                              hipStream_t stream) {
    const float* xyz = (const float*)d_in[0];
    float* out = (float*)d_out;
    int* ws = (int*)d_ws;

    const int N = in_sizes[0] / 3;                          // 4096
    const int P = (int)((long long)N * (N - 1) / 2);        // 8,386,560

    const int nb = (P + 2047) / 2048;                       // 8 pairs/thread -> 4095
    const int cap = (int)(ws_size / 4);

    if (cap >= nb + 1) {
        // fused path: ws[0..nb) per-block counts, ws[nb] ticket (zeroed here)
        hipMemsetAsync(ws + nb, 0, sizeof(int), stream);
        nl_kernel<<<nb, 256, 0, stream>>>(xyz, out, ws, N, P, nb, 1);
    } else {
        const int slots = (cap < 1 ? 1 : (cap > 1024 ? 1024 : cap));
        zero_ws<<<(slots + 255) / 256, 256, 0, stream>>>(ws, slots);
        nl_kernel<<<nb, 256, 0, stream>>>(xyz, out, ws, N, P, slots, 0);
        finalize_kernel<<<1, 256, 0, stream>>>(out, ws, slots, 6 * P);
    }
}

// Round 7
// 43.238 us; speedup vs baseline: 9.6517x; 9.6517x over previous
//
#include <hip/hip_runtime.h>

// NeighborList: N=4096, cutoff 5.0, all pairs i<j (P = N(N-1)/2 = 8,386,560).
// Output (floats): [0,P) pair_i | [P,2P) pair_j | [2P,5P) diff[P,3] | [5P,6P) dist | [6P] n_pairs
//
// R6 = R2 structure (the 45.4 us version) + sqrtf row-inversion + grid-stride
// 2048 persistent blocks (same launch shape as the 6.7 TB/s harness fill).
// Lessons enforced: NO nontemporal stores (R3: 3x BW loss), NO agent-scope
// fences/atomics in the bulk path (R5: per-block L2 drain -> 16x loss, 1.9x
// write amplification), thread-contiguous 4-pair mapping (full-line wave
// stores). Counts: register-accumulated, one plain store per block; separate
// finalize kernel (kernel boundary = coherence point).

typedef float f4 __attribute__((ext_vector_type(4)));

#define NBLK 2048

__global__ void zero_ws(int* __restrict__ ws, int n) {
    int t = blockIdx.x * blockDim.x + threadIdx.x;
    if (t < n) ws[t] = 0;
}

__global__ __launch_bounds__(256) void nl_kernel(const float* __restrict__ xyz,
                                                 float* __restrict__ out,
                                                 int* __restrict__ ws,
                                                 int N, int P, int slots) {
    const int gsize = (int)gridDim.x * 256;      // threads in grid
    const int span = gsize * 4;                  // pairs per iteration
    int cnt = 0;

    for (int it_base = 0; it_base < P; it_base += span) {
        const int p0 = it_base + ((int)blockIdx.x * 256 + (int)threadIdx.x) * 4;
        if (p0 >= P) break;

        // invert p -> row i: rowstart(i) = i*(2N-1-i)/2 <= p0. Radicand is an
        // exact int (<2^27) so sqrtf gives i within +-2; int fixups make exact.
        const int twoNm1 = 2 * N - 1;
        const long long rad = (long long)twoNm1 * twoNm1 - 8LL * (long long)p0;
        const float s = sqrtf((float)rad);
        int i = (int)(((float)twoNm1 - s) * 0.5f);
        if (i > N - 2) i = N - 2;
        if (i < 0) i = 0;
        int rs = i * (2 * N - 1 - i) / 2;
        while (p0 < rs) { --i; rs -= (N - 1 - i); }
        int next = rs + (N - 1 - i);
        while (p0 >= next && i < N - 2) { ++i; rs = next; next += (N - 1 - i); }

        float iv[4], jv[4], dxs[4], dys[4], dzs[4], dv[4];
        #pragma unroll
        for (int e = 0; e < 4; ++e) {
            const int p = p0 + e;
            while (p >= next && i < N - 2) { ++i; rs = next; next += (N - 1 - i); }
            const int j = i + 1 + (p - rs);
            float dx = 0.f, dy = 0.f, dz = 0.f, dist = 0.f, fi = -1.f, fj = -1.f;
            if (p < P) {
                const float ax = xyz[3 * i], ay = xyz[3 * i + 1], az = xyz[3 * i + 2];
                const float bx = xyz[3 * j], by = xyz[3 * j + 1], bz = xyz[3 * j + 2];
                const float tx = ax - bx, ty = ay - by, tz = az - bz;
                const float d = sqrtf(tx * tx + ty * ty + tz * tz);
                if (d < 5.0f) {                  // mirror reference: sqrt then compare
                    fi = (float)i; fj = (float)j;
                    dx = tx; dy = ty; dz = tz; dist = d;
                    ++cnt;
                }
            }
            iv[e] = fi; jv[e] = fj; dxs[e] = dx; dys[e] = dy; dzs[e] = dz; dv[e] = dist;
        }

        if (p0 + 4 <= P) {   // p0 mult of 4 -> all 16B-aligned; wave-contiguous
            *(f4*)(out + p0)     = (f4){iv[0], iv[1], iv[2], iv[3]};
            *(f4*)(out + P + p0) = (f4){jv[0], jv[1], jv[2], jv[3]};
            f4* dp = (f4*)(out + 2 * P + 3 * p0);
            dp[0] = (f4){dxs[0], dys[0], dzs[0], dxs[1]};
            dp[1] = (f4){dys[1], dzs[1], dxs[2], dys[2]};
            dp[2] = (f4){dzs[2], dxs[3], dys[3], dzs[3]};
            *(f4*)(out + 5 * P + p0) = (f4){dv[0], dv[1], dv[2], dv[3]};
        } else {
            for (int e = 0; e < 4 && p0 + e < P; ++e) {
                const int p = p0 + e;
                out[p] = iv[e]; out[P + p] = jv[e];
                out[2 * P + 3 * p]     = dxs[e];
                out[2 * P + 3 * p + 1] = dys[e];
                out[2 * P + 3 * p + 2] = dzs[e];
                out[5 * P + p] = dv[e];
            }
        }
    }

    // block-level count reduce -> one plain store (no atomics, no fences)
    for (int o = 32; o > 0; o >>= 1) cnt += __shfl_down(cnt, o, 64);
    __shared__ int sh[4];
    if ((threadIdx.x & 63) == 0) sh[threadIdx.x >> 6] = cnt;
    __syncthreads();
    if (threadIdx.x == 0) {
        const int c = sh[0] + sh[1] + sh[2] + sh[3];
        if ((int)gridDim.x <= slots) ws[blockIdx.x] = c;
        else if (c) atomicAdd(&ws[blockIdx.x % slots], c);
    }
}

__global__ void finalize_kernel(float* __restrict__ out, const int* __restrict__ ws,
                                int n, int pos) {
    const int t = threadIdx.x;  // 256
    int s = 0;
    for (int k = t; k < n; k += 256) s += ws[k];
    for (int o = 32; o > 0; o >>= 1) s += __shfl_down(s, o, 64);
    __shared__ int sh[4];
    if ((t & 63) == 0) sh[t >> 6] = s;
    __syncthreads();
    if (t == 0) out[pos] = (float)(sh[0] + sh[1] + sh[2] + sh[3]);
}

extern "C" void kernel_launch(void* const* d_in, const int* in_sizes, int n_in,
                              void* d_out, int out_size, void* d_ws, size_t ws_size,
                              hipStream_t stream) {
    const float* xyz = (const float*)d_in[0];
    float* out = (float*)d_out;
    int* ws = (int*)d_ws;

    const int N = in_sizes[0] / 3;                          // 4096
    const int P = (int)((long long)N * (N - 1) / 2);        // 8,386,560

    const int cap = (int)(ws_size / 4);
    const int slots = (NBLK <= cap) ? NBLK : (cap < 1 ? 1 : cap);
    if (NBLK > slots) zero_ws<<<(slots + 255) / 256, 256, 0, stream>>>(ws, slots);

    nl_kernel<<<NBLK, 256, 0, stream>>>(xyz, out, ws, N, P, slots);
    finalize_kernel<<<1, 256, 0, stream>>>(out, ws, slots, 6 * P);
}